// Round 12
// baseline (214.152 us; speedup 1.0000x reference)
//
#include <hip/hip_runtime.h>

typedef unsigned short u16;
typedef unsigned int u32;
typedef __attribute__((ext_vector_type(8))) short bf16x8;
typedef __attribute__((ext_vector_type(8))) _Float16 f16x8;
typedef __attribute__((ext_vector_type(4))) float f32x4;

__device__ inline u16 f2bf(float f){
  union { float f; unsigned u; } v; v.f = f;
  unsigned r = v.u + 0x7FFFu + ((v.u >> 16) & 1u);
  return (u16)(r >> 16);
}
__device__ inline float bf2f(u16 u){
  union { unsigned u; float f; } v; v.u = ((unsigned)u) << 16;
  return v.f;
}
__device__ inline u16 f2h(float f){
  union { _Float16 h; u16 u; } v; v.h = (_Float16)f; return v.u;
}

// async 16B/lane global->LDS. lds dest is wave-uniform base + lane*16 (HW).
__device__ inline void gload16(const u16* g, u16* l){
  __builtin_amdgcn_global_load_lds(
      (const __attribute__((address_space(1))) u32*)(const void*)g,
      (__attribute__((address_space(3))) u32*)(void*)l, 16, 0, 0);
}

#define WAITV(n) asm volatile("s_waitcnt vmcnt(" #n ")" ::: "memory")
#define LGKM0()  do{ asm volatile("s_waitcnt lgkmcnt(0)" ::: "memory"); \
                     __builtin_amdgcn_sched_barrier(0); }while(0)
#define FENCE()  asm volatile("" ::: "memory")

// ---------------- prep: split fp32 -> bf16 hi/lo (weights) ----------------
__global__ __launch_bounds__(256) void split_f32(const float* __restrict__ x,
                                                 u16* __restrict__ hi,
                                                 u16* __restrict__ lo, int n4){
  int i = blockIdx.x * 256 + threadIdx.x;
  if (i >= n4) return;
  float4 v = ((const float4*)x)[i];
  float a0 = v.x, a1 = v.y, a2 = v.z, a3 = v.w;
  u16 h0 = f2bf(a0), h1 = f2bf(a1), h2 = f2bf(a2), h3 = f2bf(a3);
  ushort4 h; h.x = h0; h.y = h1; h.z = h2; h.w = h3;
  ushort4 l; l.x = f2bf(a0 - bf2f(h0)); l.y = f2bf(a1 - bf2f(h1));
  l.z = f2bf(a2 - bf2f(h2)); l.w = f2bf(a3 - bf2f(h3));
  ((ushort4*)hi)[i] = h;
  ((ushort4*)lo)[i] = l;
}

// ---------------- prep: z -> bf16 hi + fp16 copy ----------------
__global__ __launch_bounds__(256) void split_z(const float* __restrict__ x,
                                               u16* __restrict__ hi,
                                               u16* __restrict__ h16, int n4){
  int i = blockIdx.x * 256 + threadIdx.x;
  if (i >= n4) return;
  float4 v = ((const float4*)x)[i];
  ushort4 h; h.x = f2bf(v.x); h.y = f2bf(v.y); h.z = f2bf(v.z); h.w = f2bf(v.w);
  ushort4 g; g.x = f2h(v.x); g.y = f2h(v.y); g.z = f2h(v.z); g.w = f2h(v.w);
  ((ushort4*)hi)[i] = h;
  ((ushort4*)h16)[i] = g;
}

// ---------------- prep: transpose Wv -> bf16 (hi only) ----------------
__global__ __launch_bounds__(256) void transpose_wv(
    const float* __restrict__ W, u16* __restrict__ H){
  __shared__ float t[64][65];
  int d0 = blockIdx.y * 64, n0 = blockIdx.x * 64;
  int tid = threadIdx.x;
  int r = tid >> 4, c4 = (tid & 15) * 4;
  for (int rr = r; rr < 64; rr += 16){
    float4 v = *(const float4*)&W[(size_t)(d0 + rr) * 1024 + n0 + c4];
    t[rr][c4 + 0] = v.x; t[rr][c4 + 1] = v.y; t[rr][c4 + 2] = v.z; t[rr][c4 + 3] = v.w;
  }
  __syncthreads();
  int n = tid >> 4, d4 = (tid & 15) * 4;
  for (int nn = n; nn < 64; nn += 16){
    ushort4 h;
    h.x = f2bf(t[d4 + 0][nn]); h.y = f2bf(t[d4 + 1][nn]);
    h.z = f2bf(t[d4 + 2][nn]); h.w = f2bf(t[d4 + 3][nn]);
    *(ushort4*)&H[(size_t)(n0 + nn) * 1024 + d0 + d4] = h;
  }
}

// ---------------- small GEMM (128x128 tile, 4 waves) ----------------
// IN: 0 = bf16 split (hi/lo, 3-MFMA chain), 1 = bf16 single. EPI: 1 = fp16 out.
template<int IN, int EPI>
__global__ __launch_bounds__(256) void gemm_bt(
    const u16* __restrict__ Ah, const u16* __restrict__ Al, int lda,
    const u16* __restrict__ Bh, const u16* __restrict__ Bl, int ldb,
    void* __restrict__ C0, int ldc, int K){
  constexpr int NPL = (IN == 0) ? 4 : 2;
  constexpr int DEPTH = (IN == 0) ? 1 : 2;
  constexpr int NBUF = DEPTH + 1;
  __shared__ __align__(16) u16 sm[NBUF * NPL * 4096];

  const int tid = threadIdx.x;
  const int lane = tid & 63, wave = tid >> 6;
  const int wr = wave >> 1, wc = wave & 1;
  const int lr = lane & 15, kg = lane >> 4;

  const int nwg = gridDim.x * gridDim.y;
  const int id = blockIdx.y * gridDim.x + blockIdx.x;
  const int chunk = nwg >> 3;
  const int swz = (id & 7) * chunk + (id >> 3);
  const int bx = swz % gridDim.x, by = swz / gridDim.x;
  const int m0 = by * 128, n0 = bx * 128;

  const int l_r = lane >> 2, l_c = lane & 3;
  const int st_chunk = l_c ^ ((l_r + (l_r >> 2)) & 3);
  const int rd_swz = (lr + (lr >> 2)) & 3;

  f32x4 acc[4][4];
  #pragma unroll
  for (int m = 0; m < 4; m++)
    #pragma unroll
    for (int n = 0; n < 4; n++)
      acc[m][n] = (f32x4){0.f, 0.f, 0.f, 0.f};

  auto STAGE = [&](int buf, int k0){
    #pragma unroll
    for (int c = 0; c < NPL * 2; ++c){
      int pc = c * 4 + wave;
      int p = pc >> 3, ch = pc & 7;
      const u16* g; int ld, rb;
      if (IN == 0){
        g = (p == 0) ? Ah : (p == 1) ? Al : (p == 2) ? Bh : Bl;
        ld = (p < 2) ? lda : ldb;  rb = (p < 2) ? m0 : n0;
      } else {
        g = (p == 0) ? Ah : Bh;
        ld = (p == 0) ? lda : ldb; rb = (p == 0) ? m0 : n0;
      }
      int r = ch * 16 + l_r;
      const u16* src = g + (size_t)(rb + r) * ld + k0 + st_chunk * 8;
      u16* dst = &sm[((size_t)buf * NPL + p) * 4096 + ch * 512];
      gload16(src, dst);
    }
  };

  const int KT = K >> 5;
  STAGE(0, 0);
  if constexpr (DEPTH == 2){ if (KT > 1) STAGE(1, 32); }

  int bufc = 0, pfb = DEPTH % NBUF;
  for (int kt = 0; kt < KT; ++kt){
    const int pf = kt + DEPTH;
    if (pf < KT){
      STAGE(pfb, pf * 32);
      WAITV(8);
    } else if (kt + 1 < KT){
      if constexpr (IN == 0) WAITV(8); else WAITV(4);
    } else {
      WAITV(0);
    }
    __builtin_amdgcn_s_barrier();
    FENCE();

    const u16* pA  = &sm[((size_t)bufc * NPL + 0) * 4096];
    const u16* pAl = &sm[((size_t)bufc * NPL + 1) * 4096];
    const u16* pB  = &sm[((size_t)bufc * NPL + (IN == 0 ? 2 : 1)) * 4096];
    const u16* pBl = &sm[((size_t)bufc * NPL + 3) * 4096];

    const int slot = (kg ^ rd_swz) * 8;
    bf16x8 afh[4], bfh[4], afl[4], bfl[4];
    #pragma unroll
    for (int m = 0; m < 4; m++){
      int r = wr * 64 + m * 16 + lr;
      afh[m] = *(const bf16x8*)&pA[r * 32 + slot];
      if (IN == 0) afl[m] = *(const bf16x8*)&pAl[r * 32 + slot];
    }
    #pragma unroll
    for (int n = 0; n < 4; n++){
      int r = wc * 64 + n * 16 + lr;
      bfh[n] = *(const bf16x8*)&pB[r * 32 + slot];
      if (IN == 0) bfl[n] = *(const bf16x8*)&pBl[r * 32 + slot];
    }
    #pragma unroll
    for (int m = 0; m < 4; m++)
      #pragma unroll
      for (int n = 0; n < 4; n++){
        acc[m][n] = __builtin_amdgcn_mfma_f32_16x16x32_bf16(afh[m], bfh[n], acc[m][n], 0, 0, 0);
        if (IN == 0){
          acc[m][n] = __builtin_amdgcn_mfma_f32_16x16x32_bf16(afl[m], bfh[n], acc[m][n], 0, 0, 0);
          acc[m][n] = __builtin_amdgcn_mfma_f32_16x16x32_bf16(afh[m], bfl[n], acc[m][n], 0, 0, 0);
        }
      }
    FENCE();
    __builtin_amdgcn_s_barrier();
    bufc = (bufc + 1 == NBUF) ? 0 : bufc + 1;
    pfb  = (pfb  + 1 == NBUF) ? 0 : pfb  + 1;
  }

  const int row0 = m0 + wr * 64, col0 = n0 + wc * 64 + lr;
  #pragma unroll
  for (int m = 0; m < 4; m++)
    #pragma unroll
    for (int n = 0; n < 4; n++)
      #pragma unroll
      for (int r = 0; r < 4; r++){
        int row = row0 + m * 16 + kg * 4 + r;
        int col = col0 + n * 16;
        ((u16*)C0)[(size_t)row * ldc + col] = f2h(acc[m][n][r]);
      }
}

// ---------------- big GEMM: 256x256, BK=64, 4-phase counted-vmcnt ----------
// fp16 in, fp32 out. LDS = 2buf x {A,B} x {ks0,ks1} planes of [256][32] u16
// (128KB). Quarter-staging: each phase issues 2 gloads for ONE (op,ks) plane
// of tile kt+1. Per phase: {ds_read subtile; stage; [vmcnt(4) at ph1/ph3];
// barrier; lgkmcnt(0)+sched_barrier; setprio(1) 16 MFMA setprio(0); barrier}.
// vmcnt(4) waits only for loads >=3 phases old (never drains); the following
// barrier makes the per-wave guarantee collective. Swizzle: slot =
// kg ^ ((row>>1)&3) -> 2-way bank alias (free, m136); staging pre-swizzles
// the global source so the linear gload_lds dest matches.
__global__ __launch_bounds__(512, 1) void gemm256(
    const u16* __restrict__ A, int lda,
    const u16* __restrict__ B, int ldb,
    float* __restrict__ C0z, int l0, float* __restrict__ C1z, int l1,
    float* __restrict__ C2z, int l2, float* __restrict__ C3z, int l3,
    int K){
  __shared__ __align__(16) u16 sm[8 * 8192];   // [buf][op][ks] planes

  const int tid = threadIdx.x;
  const int lane = tid & 63, wave = tid >> 6;
  const int wr = wave >> 2, wc = wave & 3;        // 2 x 4 waves
  const int lr = lane & 15, kg = lane >> 4;

  const int nwg = gridDim.x * gridDim.y;
  const int id = blockIdx.y * gridDim.x + blockIdx.x;
  const int chunk = nwg >> 3;
  const int swz = (id & 7) * chunk + (id >> 3);
  const int bx = swz % gridDim.x, by = swz / gridDim.x;
  const int m0 = by * 256, n0 = bx * 256;

  A += (size_t)blockIdx.z * (size_t)K;
  B += (size_t)blockIdx.z * (size_t)K;
  float* Cp; int ldc;
  if (blockIdx.z == 0){ Cp = C0z; ldc = l0; }
  else if (blockIdx.z == 1){ Cp = C1z; ldc = l1; }
  else if (blockIdx.z == 2){ Cp = C2z; ldc = l2; }
  else { Cp = C3z; ldc = l3; }

  // stage one (op,ks) plane of a buffer: 2 gloads/lane, 256 rows x 32 cols
  auto STAGE_Q = [&](int buf, int k0, int op, int ks){
    const u16* g = op ? B : A;
    int ld = op ? ldb : lda;
    int rb = op ? n0 : m0;
    u16* plane = &sm[(size_t)(((buf * 2 + op) * 2 + ks)) * 8192];
    #pragma unroll
    for (int r = 0; r < 2; ++r){
      int r0 = r * 128 + wave * 16;
      int grow = rb + r0 + (lane >> 2);
      int gcol = k0 + ks * 32 + (((lane & 3) ^ ((lane >> 3) & 3)) * 8);
      gload16(g + (size_t)grow * ld + gcol, plane + r0 * 32);
    }
  };

  f32x4 acc[8][4];
  #pragma unroll
  for (int m = 0; m < 8; m++)
    #pragma unroll
    for (int n = 0; n < 4; n++)
      acc[m][n] = (f32x4){0.f, 0.f, 0.f, 0.f};

  const int KT = K >> 6;
  STAGE_Q(0, 0, 0, 0); STAGE_Q(0, 0, 1, 0);
  STAGE_Q(0, 0, 0, 1); STAGE_Q(0, 0, 1, 1);
  WAITV(0);
  __builtin_amdgcn_s_barrier();
  FENCE();

  int bufc = 0;
  for (int kt = 0; kt < KT; ++kt){
    const int nb = bufc ^ 1;
    const bool pf = (kt + 1 < KT);
    const int pk = (kt + 1) * 64;
    f16x8 b[4], a[4];

    #pragma unroll
    for (int ks = 0; ks < 2; ++ks){
      const u16* pA = &sm[(size_t)((bufc * 2 + 0) * 2 + ks) * 8192];
      const u16* pB = &sm[(size_t)((bufc * 2 + 1) * 2 + ks) * 8192];

      // ---- phase (ks,0): b[0..3] + a[0..3]; stage A-plane(ks) of kt+1 ----
      #pragma unroll
      for (int n = 0; n < 4; n++){
        int R = wc * 64 + n * 16 + lr;
        b[n] = *(const f16x8*)&pB[R * 32 + ((kg ^ ((R >> 1) & 3)) * 8)];
      }
      #pragma unroll
      for (int m = 0; m < 4; m++){
        int R = wr * 128 + m * 16 + lr;
        a[m] = *(const f16x8*)&pA[R * 32 + ((kg ^ ((R >> 1) & 3)) * 8)];
      }
      if (pf) STAGE_Q(nb, pk, 0, ks);
      FENCE();
      __builtin_amdgcn_s_barrier();
      LGKM0();
      __builtin_amdgcn_s_setprio(1);
      #pragma unroll
      for (int m = 0; m < 4; m++)
        #pragma unroll
        for (int n = 0; n < 4; n++)
          acc[m][n] = __builtin_amdgcn_mfma_f32_16x16x32_f16(a[m], b[n], acc[m][n], 0, 0, 0);
      __builtin_amdgcn_s_setprio(0);
      FENCE();
      __builtin_amdgcn_s_barrier();

      // ---- phase (ks,1): a[4..7]; stage B-plane(ks) of kt+1; vmcnt ----
      #pragma unroll
      for (int m = 0; m < 4; m++){
        int R = wr * 128 + (m + 4) * 16 + lr;
        a[m] = *(const f16x8*)&pA[R * 32 + ((kg ^ ((R >> 1) & 3)) * 8)];
      }
      if (pf) STAGE_Q(nb, pk, 1, ks);
      // counted wait: clears the 4 oldest outstanding loads (>=3 phases old).
      // ks=0: clears Q2,Q3(kt) [A/B-ks1 of current] -> ks1 phases safe.
      // ks=1: clears Q0',Q1'(kt+1) [A/B-ks0 of next] -> next ph0 safe.
      if (pf) WAITV(4); else WAITV(0);
      FENCE();
      __builtin_amdgcn_s_barrier();
      LGKM0();
      __builtin_amdgcn_s_setprio(1);
      #pragma unroll
      for (int m = 0; m < 4; m++)
        #pragma unroll
        for (int n = 0; n < 4; n++)
          acc[m + 4][n] = __builtin_amdgcn_mfma_f32_16x16x32_f16(a[m], b[n], acc[m + 4][n], 0, 0, 0);
      __builtin_amdgcn_s_setprio(0);
      FENCE();
      __builtin_amdgcn_s_barrier();
    }
    bufc ^= 1;
  }

  const int row0 = m0 + wr * 128, col0 = n0 + wc * 64 + lr;
  #pragma unroll
  for (int m = 0; m < 8; m++)
    #pragma unroll
    for (int n = 0; n < 4; n++)
      #pragma unroll
      for (int r = 0; r < 4; r++){
        int row = row0 + m * 16 + kg * 4 + r;
        int col = col0 + n * 16;
        Cp[(size_t)row * ldc + col] = acc[m][n][r];
      }
}

// ---------------- reduce: t16 = fp16(s0+s1+s2+s3) ----------------
__global__ __launch_bounds__(256) void reduce_t(u16* __restrict__ t16,
                                                const float* __restrict__ s0,
                                                const float* __restrict__ s1,
                                                const float* __restrict__ s2,
                                                const float* __restrict__ s3){
  int idx = blockIdx.x * 256 + threadIdx.x;
  float4 a = ((const float4*)s0)[idx];
  float4 b = ((const float4*)s1)[idx];
  float4 c = ((const float4*)s2)[idx];
  float4 d = ((const float4*)s3)[idx];
  ushort4 o;
  o.x = f2h((a.x + b.x) + (c.x + d.x));
  o.y = f2h((a.y + b.y) + (c.y + d.y));
  o.z = f2h((a.z + b.z) + (c.z + d.z));
  o.w = f2h((a.w + b.w) + (c.w + d.w));
  ((ushort4*)t16)[idx] = o;
}

// ---------------- reduce: out += hole1 + hole2 + slab3 ----------------
__global__ __launch_bounds__(256) void reduce_pv(float* __restrict__ out,
                                                 const float* __restrict__ Sf,
                                                 const float* __restrict__ s3){
  int idx = blockIdx.x * 256 + threadIdx.x;
  int r = idx >> 8, c4 = (idx & 255) * 4;
  float4 a = ((const float4*)out)[idx];
  float4 b = ((const float4*)s3)[idx];
  float4 h1 = *(const float4*)&Sf[(size_t)r * 4096 + 2048 + c4];
  float4 h2 = *(const float4*)&Sf[(size_t)r * 4096 + 3072 + c4];
  float4 o;
  o.x = (a.x + b.x) + (h1.x + h2.x);
  o.y = (a.y + b.y) + (h1.y + h2.y);
  o.z = (a.z + b.z) + (h1.z + h2.z);
  o.w = (a.w + b.w) + (h1.w + h2.w);
  ((float4*)out)[idx] = o;
}

// ---------------- softmax over rows of S (4096 fp32), write P fp16 in-place -
__global__ __launch_bounds__(256) void softmax_rows(float* __restrict__ S){
  int rrow = blockIdx.x;
  float* srow = S + (size_t)rrow * 4096;
  __shared__ float e[4096];
  __shared__ float red[4];
  int tid = threadIdx.x;

  float m = -1e30f;
  for (int i = tid * 4; i < 4096; i += 1024){
    float4 v = *(const float4*)(srow + i);
    m = fmaxf(m, fmaxf(fmaxf(v.x, v.y), fmaxf(v.z, v.w)));
  }
  for (int o = 32; o > 0; o >>= 1) m = fmaxf(m, __shfl_xor(m, o));
  if ((tid & 63) == 0) red[tid >> 6] = m;
  __syncthreads();
  m = fmaxf(fmaxf(red[0], red[1]), fmaxf(red[2], red[3]));

  float s = 0.f;
  for (int i = tid * 4; i < 4096; i += 1024){
    float4 v = *(const float4*)(srow + i);
    float4 ev;
    ev.x = __expf(v.x - m); ev.y = __expf(v.y - m);
    ev.z = __expf(v.z - m); ev.w = __expf(v.w - m);
    s += (ev.x + ev.y) + (ev.z + ev.w);
    *(float4*)&e[i] = ev;
  }
  for (int o = 32; o > 0; o >>= 1) s += __shfl_xor(s, o);
  __syncthreads();
  if ((tid & 63) == 0) red[tid >> 6] = s;
  __syncthreads();
  s = (red[0] + red[1]) + (red[2] + red[3]);

  float scale = 0.03125f / s;    // fold post-softmax 1/sqrt(dk)=1/32 into P
  u16* prow = (u16*)((char*)S + (size_t)rrow * 16384);
  for (int i = tid * 4; i < 4096; i += 1024){
    float4 v = *(const float4*)&e[i];
    ushort4 o; o.x = f2h(v.x * scale); o.y = f2h(v.y * scale);
    o.z = f2h(v.z * scale); o.w = f2h(v.w * scale);
    *(ushort4*)(prow + i) = o;
  }
}

extern "C" void kernel_launch(void* const* d_in, const int* in_sizes, int n_in,
                              void* d_out, int out_size, void* d_ws, size_t ws_size,
                              hipStream_t stream){
  const float* z  = (const float*)d_in[0];
  const float* Wq = (const float*)d_in[1];
  const float* Wk = (const float*)d_in[2];
  const float* Wv = (const float*)d_in[3];
  char* ws = (char*)d_ws;
  const size_t MB = 1ull << 20;

  // layout: 0-8 t16 | 8-16 z16 | 16-24 vt16 | 24-88 S fp32 / t-slabs | 88-90 m16
  u16* t16   = (u16*)(ws + 0 * MB);
  u16* z16   = (u16*)(ws + 8 * MB);
  u16* vt16  = (u16*)(ws + 16 * MB);
  float* S   = (float*)(ws + 24 * MB);
  u16* m16   = (u16*)(ws + 88 * MB);
  float* slab3 = (float*)(ws + 0 * MB);           // PV partial (t16/z16 dead)
  float* ts0 = (float*)(ws + 24 * MB);            // t partial slabs
  float* ts1 = (float*)(ws + 40 * MB);
  float* ts2 = (float*)(ws + 56 * MB);
  float* ts3 = (float*)(ws + 72 * MB);
  // prep scratch (dead before region reuse):
  u16* z_hi  = (u16*)(ws + 24 * MB);
  u16* wqh   = (u16*)(ws + 40 * MB);
  u16* wql   = (u16*)(ws + 42 * MB);
  u16* wkh   = (u16*)(ws + 44 * MB);
  u16* wkl   = (u16*)(ws + 46 * MB);
  u16* wvt_h = (u16*)(ws + 48 * MB);

  split_z<<<4096, 256, 0, stream>>>(z, z_hi, z16, 4096 * 1024 / 4);
  split_f32<<<1024, 256, 0, stream>>>(Wq, wqh, wql, 1024 * 1024 / 4);
  split_f32<<<1024, 256, 0, stream>>>(Wk, wkh, wkl, 1024 * 1024 / 4);
  transpose_wv<<<dim3(16, 16), 256, 0, stream>>>(Wv, wvt_h);

  // m16[m,n] = sum_e Wk[m,e] Wq[n,e]  (split x split, fp16 out)  1024^3
  gemm_bt<0, 1><<<dim3(8, 8), 256, 0, stream>>>(wkh, wkl, 1024,
      wqh, wql, 1024, m16, 1024, 1024);

  // v^T = Wv^T x z (bf16 single, fp16 out)  M=1024 N=4096 K=1024
  gemm_bt<1, 1><<<dim3(32, 8), 256, 0, stream>>>(wvt_h, nullptr, 1024,
      z_hi, nullptr, 1024, vt16, 4096, 1024);

  // t = z16 @ m16^T, split-K=4 (K=256/slice) -> fp32 slabs
  gemm256<<<dim3(4, 16, 4), 512, 0, stream>>>(z16, 1024, m16, 1024,
      ts0, 1024, ts1, 1024, ts2, 1024, ts3, 1024, 256);
  reduce_t<<<4096, 256, 0, stream>>>(t16, ts0, ts1, ts2, ts3);

  // S = t16 @ z16^T  fp32  M=N=4096 K=1024
  gemm256<<<dim3(16, 16, 1), 512, 0, stream>>>(t16, 1024, z16, 1024,
      S, 4096, S, 4096, S, 4096, S, 4096, 1024);

  // softmax rows -> P fp16 in-place (stride 8192 u16), 1/32 folded in
  softmax_rows<<<4096, 256, 0, stream>>>(S);

  // out = P @ v, split-K=4. partials: z0 -> d_out, z1/z2 -> holes, z3 -> slab3
  gemm256<<<dim3(4, 16, 4), 512, 0, stream>>>((u16*)S, 8192, vt16, 4096,
      (float*)d_out, 1024, S + 2048, 4096, S + 3072, 4096, slab3, 1024, 1024);

  // out += hole1 + hole2 + slab3
  reduce_pv<<<4096, 256, 0, stream>>>((float*)d_out, S, slab3);
}

// Round 13
// 192.020 us; speedup vs baseline: 1.1153x; 1.1153x over previous
//
#include <hip/hip_runtime.h>

typedef unsigned short u16;
typedef unsigned int u32;
typedef __attribute__((ext_vector_type(8))) short bf16x8;
typedef __attribute__((ext_vector_type(8))) _Float16 f16x8;
typedef __attribute__((ext_vector_type(4))) float f32x4;

__device__ inline u16 f2bf(float f){
  union { float f; unsigned u; } v; v.f = f;
  unsigned r = v.u + 0x7FFFu + ((v.u >> 16) & 1u);
  return (u16)(r >> 16);
}
__device__ inline float bf2f(u16 u){
  union { unsigned u; float f; } v; v.u = ((unsigned)u) << 16;
  return v.f;
}
__device__ inline u16 f2h(float f){
  union { _Float16 h; u16 u; } v; v.h = (_Float16)f; return v.u;
}

// async 16B/lane global->LDS. lds dest is wave-uniform base + lane*16 (HW).
__device__ inline void gload16(const u16* g, u16* l){
  __builtin_amdgcn_global_load_lds(
      (const __attribute__((address_space(1))) u32*)(const void*)g,
      (__attribute__((address_space(3))) u32*)(void*)l, 16, 0, 0);
}

#define WAITV(n) asm volatile("s_waitcnt vmcnt(" #n ")" ::: "memory")
#define FENCE()  asm volatile("" ::: "memory")

// ---------------- prep: split fp32 -> bf16 hi/lo (weights) ----------------
__global__ __launch_bounds__(256) void split_f32(const float* __restrict__ x,
                                                 u16* __restrict__ hi,
                                                 u16* __restrict__ lo, int n4){
  int i = blockIdx.x * 256 + threadIdx.x;
  if (i >= n4) return;
  float4 v = ((const float4*)x)[i];
  float a0 = v.x, a1 = v.y, a2 = v.z, a3 = v.w;
  u16 h0 = f2bf(a0), h1 = f2bf(a1), h2 = f2bf(a2), h3 = f2bf(a3);
  ushort4 h; h.x = h0; h.y = h1; h.z = h2; h.w = h3;
  ushort4 l; l.x = f2bf(a0 - bf2f(h0)); l.y = f2bf(a1 - bf2f(h1));
  l.z = f2bf(a2 - bf2f(h2)); l.w = f2bf(a3 - bf2f(h3));
  ((ushort4*)hi)[i] = h;
  ((ushort4*)lo)[i] = l;
}

// ---------------- prep: z -> bf16 hi + fp16 copy ----------------
__global__ __launch_bounds__(256) void split_z(const float* __restrict__ x,
                                               u16* __restrict__ hi,
                                               u16* __restrict__ h16, int n4){
  int i = blockIdx.x * 256 + threadIdx.x;
  if (i >= n4) return;
  float4 v = ((const float4*)x)[i];
  ushort4 h; h.x = f2bf(v.x); h.y = f2bf(v.y); h.z = f2bf(v.z); h.w = f2bf(v.w);
  ushort4 g; g.x = f2h(v.x); g.y = f2h(v.y); g.z = f2h(v.z); g.w = f2h(v.w);
  ((ushort4*)hi)[i] = h;
  ((ushort4*)h16)[i] = g;
}

// ---------------- prep: transpose Wv -> bf16 (hi only) ----------------
__global__ __launch_bounds__(256) void transpose_wv(
    const float* __restrict__ W, u16* __restrict__ H){
  __shared__ float t[64][65];
  int d0 = blockIdx.y * 64, n0 = blockIdx.x * 64;
  int tid = threadIdx.x;
  int r = tid >> 4, c4 = (tid & 15) * 4;
  for (int rr = r; rr < 64; rr += 16){
    float4 v = *(const float4*)&W[(size_t)(d0 + rr) * 1024 + n0 + c4];
    t[rr][c4 + 0] = v.x; t[rr][c4 + 1] = v.y; t[rr][c4 + 2] = v.z; t[rr][c4 + 3] = v.w;
  }
  __syncthreads();
  int n = tid >> 4, d4 = (tid & 15) * 4;
  for (int nn = n; nn < 64; nn += 16){
    ushort4 h;
    h.x = f2bf(t[d4 + 0][nn]); h.y = f2bf(t[d4 + 1][nn]);
    h.z = f2bf(t[d4 + 2][nn]); h.w = f2bf(t[d4 + 3][nn]);
    *(ushort4*)&H[(size_t)(n0 + nn) * 1024 + d0 + d4] = h;
  }
}

// ---------------- small GEMM (128x128 tile, 4 waves) ----------------
// IN: 0 = bf16 split (hi/lo, 3-MFMA chain), 1 = bf16 single, 2 = fp16 single.
// EPI: 0 = fp32 out into slab blockIdx.z*zslab; 1 = fp16 out.
// Split-K via blockIdx.z: operands offset by z*K columns.
template<int IN, int EPI>
__global__ __launch_bounds__(256) void gemm_bt(
    const u16* __restrict__ Ah, const u16* __restrict__ Al, int lda,
    const u16* __restrict__ Bh, const u16* __restrict__ Bl, int ldb,
    void* __restrict__ C0, int ldc, int K, size_t zslab){
  constexpr int NPL = (IN == 0) ? 4 : 2;
  constexpr int DEPTH = (IN == 0) ? 1 : 2;
  constexpr int NBUF = DEPTH + 1;
  __shared__ __align__(16) u16 sm[NBUF * NPL * 4096];

  const int kz = blockIdx.z * K;
  Ah += kz; Bh += kz;
  if constexpr (IN == 0){ Al += kz; Bl += kz; }

  const int tid = threadIdx.x;
  const int lane = tid & 63, wave = tid >> 6;
  const int wr = wave >> 1, wc = wave & 1;
  const int lr = lane & 15, kg = lane >> 4;

  const int nwg = gridDim.x * gridDim.y;
  const int id = blockIdx.y * gridDim.x + blockIdx.x;
  const int chunk = nwg >> 3;
  const int swz = (id & 7) * chunk + (id >> 3);
  const int bx = swz % gridDim.x, by = swz / gridDim.x;
  const int m0 = by * 128, n0 = bx * 128;

  const int l_r = lane >> 2, l_c = lane & 3;
  const int st_chunk = l_c ^ ((l_r + (l_r >> 2)) & 3);
  const int rd_swz = (lr + (lr >> 2)) & 3;

  f32x4 acc[4][4];
  #pragma unroll
  for (int m = 0; m < 4; m++)
    #pragma unroll
    for (int n = 0; n < 4; n++)
      acc[m][n] = (f32x4){0.f, 0.f, 0.f, 0.f};

  auto STAGE = [&](int buf, int k0){
    #pragma unroll
    for (int c = 0; c < NPL * 2; ++c){
      int pc = c * 4 + wave;
      int p = pc >> 3, ch = pc & 7;
      const u16* g; int ld, rb;
      if (IN == 0){
        g = (p == 0) ? Ah : (p == 1) ? Al : (p == 2) ? Bh : Bl;
        ld = (p < 2) ? lda : ldb;  rb = (p < 2) ? m0 : n0;
      } else {
        g = (p == 0) ? Ah : Bh;
        ld = (p == 0) ? lda : ldb; rb = (p == 0) ? m0 : n0;
      }
      int r = ch * 16 + l_r;
      const u16* src = g + (size_t)(rb + r) * ld + k0 + st_chunk * 8;
      u16* dst = &sm[((size_t)buf * NPL + p) * 4096 + ch * 512];
      gload16(src, dst);
    }
  };

  const int KT = K >> 5;
  STAGE(0, 0);
  if constexpr (DEPTH == 2){ if (KT > 1) STAGE(1, 32); }

  int bufc = 0, pfb = DEPTH % NBUF;
  for (int kt = 0; kt < KT; ++kt){
    const int pf = kt + DEPTH;
    if (pf < KT){
      STAGE(pfb, pf * 32);
      WAITV(8);
    } else if (kt + 1 < KT){
      if constexpr (IN == 0) WAITV(8); else WAITV(4);
    } else {
      WAITV(0);
    }
    __builtin_amdgcn_s_barrier();
    FENCE();

    const u16* pA  = &sm[((size_t)bufc * NPL + 0) * 4096];
    const u16* pAl = &sm[((size_t)bufc * NPL + 1) * 4096];
    const u16* pB  = &sm[((size_t)bufc * NPL + (IN == 0 ? 2 : 1)) * 4096];
    const u16* pBl = &sm[((size_t)bufc * NPL + 3) * 4096];

    const int slot = (kg ^ rd_swz) * 8;
    bf16x8 afh[4], bfh[4], afl[4], bfl[4];
    f16x8 ah16[4], bh16[4];
    #pragma unroll
    for (int m = 0; m < 4; m++){
      int r = wr * 64 + m * 16 + lr;
      if (IN == 2) ah16[m] = *(const f16x8*)&pA[r * 32 + slot];
      else {
        afh[m] = *(const bf16x8*)&pA[r * 32 + slot];
        if (IN == 0) afl[m] = *(const bf16x8*)&pAl[r * 32 + slot];
      }
    }
    #pragma unroll
    for (int n = 0; n < 4; n++){
      int r = wc * 64 + n * 16 + lr;
      if (IN == 2) bh16[n] = *(const f16x8*)&pB[r * 32 + slot];
      else {
        bfh[n] = *(const bf16x8*)&pB[r * 32 + slot];
        if (IN == 0) bfl[n] = *(const bf16x8*)&pBl[r * 32 + slot];
      }
    }
    #pragma unroll
    for (int m = 0; m < 4; m++)
      #pragma unroll
      for (int n = 0; n < 4; n++){
        if (IN == 2){
          acc[m][n] = __builtin_amdgcn_mfma_f32_16x16x32_f16(ah16[m], bh16[n], acc[m][n], 0, 0, 0);
        } else {
          acc[m][n] = __builtin_amdgcn_mfma_f32_16x16x32_bf16(afh[m], bfh[n], acc[m][n], 0, 0, 0);
          if (IN == 0){
            acc[m][n] = __builtin_amdgcn_mfma_f32_16x16x32_bf16(afl[m], bfh[n], acc[m][n], 0, 0, 0);
            acc[m][n] = __builtin_amdgcn_mfma_f32_16x16x32_bf16(afh[m], bfl[n], acc[m][n], 0, 0, 0);
          }
        }
      }
    FENCE();
    __builtin_amdgcn_s_barrier();
    bufc = (bufc + 1 == NBUF) ? 0 : bufc + 1;
    pfb  = (pfb  + 1 == NBUF) ? 0 : pfb  + 1;
  }

  const int row0 = m0 + wr * 64, col0 = n0 + wc * 64 + lr;
  #pragma unroll
  for (int m = 0; m < 4; m++)
    #pragma unroll
    for (int n = 0; n < 4; n++)
      #pragma unroll
      for (int r = 0; r < 4; r++){
        int row = row0 + m * 16 + kg * 4 + r;
        int col = col0 + n * 16;
        float x = acc[m][n][r];
        if (EPI == 0){
          float* C = (float*)C0 + (size_t)blockIdx.z * zslab;
          C[(size_t)row * ldc + col] = x;
        } else {
          ((u16*)C0)[(size_t)row * ldc + col] = f2h(x);
        }
      }
}

// ---------------- big GEMM: 256x256 tile, BK=64, 8 waves, wave 128x64 ------
// fp16 in, fp32 out. (R11 schedule: best measured.) LDS 128KB = 2 bufs x
// (A 32KB + B 32KB). 8-slot XOR involution swizzle for 128B rows, zero
// bank conflicts (verified R11). One vmcnt(0)+barrier per K-tile.
__global__ __launch_bounds__(512, 1) void gemm256(
    const u16* __restrict__ A, int lda,
    const u16* __restrict__ B, int ldb,
    float* __restrict__ C0z, int l0, float* __restrict__ C1z, int l1,
    float* __restrict__ C2z, int l2, float* __restrict__ C3z, int l3,
    int K){
  __shared__ __align__(16) u16 sm[2 * 32768];

  const int tid = threadIdx.x;
  const int lane = tid & 63, wave = tid >> 6;
  const int wr = wave >> 2, wc = wave & 3;        // 2 x 4 waves
  const int lr = lane & 15, kg = lane >> 4;
  const int g7 = lr & 7;

  const int nwg = gridDim.x * gridDim.y;
  const int id = blockIdx.y * gridDim.x + blockIdx.x;
  const int chunk = nwg >> 3;
  const int swz = (id & 7) * chunk + (id >> 3);
  const int bx = swz % gridDim.x, by = swz / gridDim.x;
  const int m0 = by * 256, n0 = bx * 256;

  A += (size_t)blockIdx.z * (size_t)K;
  B += (size_t)blockIdx.z * (size_t)K;
  float* Cp; int ldc;
  if (blockIdx.z == 0){ Cp = C0z; ldc = l0; }
  else if (blockIdx.z == 1){ Cp = C1z; ldc = l1; }
  else if (blockIdx.z == 2){ Cp = C2z; ldc = l2; }
  else { Cp = C3z; ldc = l3; }

  auto STAGE = [&](int buf, int k0){
    #pragma unroll
    for (int rd = 0; rd < 8; ++rd){
      int p = rd >> 2;
      int r0 = (rd & 3) * 64 + wave * 8;
      const u16* g = p ? B : A;
      int ld = p ? ldb : lda;
      int rb = p ? n0 : m0;
      int grow = rb + r0 + (lane >> 3);
      int gch = (lane & 7) ^ (lane >> 3);
      const u16* src = g + (size_t)grow * ld + k0 + gch * 8;
      u16* dst = &sm[(size_t)buf * 32768 + p * 16384 + r0 * 64];
      gload16(src, dst);
    }
  };

  f32x4 acc[8][4];
  #pragma unroll
  for (int m = 0; m < 8; m++)
    #pragma unroll
    for (int n = 0; n < 4; n++)
      acc[m][n] = (f32x4){0.f, 0.f, 0.f, 0.f};

  const int KT = K >> 6;
  STAGE(0, 0);

  int bufc = 0;
  for (int kt = 0; kt < KT; ++kt){
    WAITV(0);
    __builtin_amdgcn_s_barrier();
    FENCE();
    if (kt + 1 < KT) STAGE(bufc ^ 1, (kt + 1) * 64);

    const u16* pA = &sm[(size_t)bufc * 32768];
    const u16* pB = pA + 16384;
    #pragma unroll
    for (int ks = 0; ks < 2; ++ks){
      f16x8 b[4], a[8];
      #pragma unroll
      for (int n = 0; n < 4; n++){
        int R = wc * 64 + n * 16 + lr;
        b[n] = *(const f16x8*)&pB[R * 64 + (((ks * 4 + kg) ^ g7) * 8)];
      }
      #pragma unroll
      for (int m = 0; m < 8; m++){
        int R = wr * 128 + m * 16 + lr;
        a[m] = *(const f16x8*)&pA[R * 64 + (((ks * 4 + kg) ^ g7) * 8)];
      }
      __builtin_amdgcn_s_setprio(1);
      #pragma unroll
      for (int m = 0; m < 8; m++)
        #pragma unroll
        for (int n = 0; n < 4; n++)
          acc[m][n] = __builtin_amdgcn_mfma_f32_16x16x32_f16(a[m], b[n], acc[m][n], 0, 0, 0);
      __builtin_amdgcn_s_setprio(0);
    }
    FENCE();
    bufc ^= 1;
  }

  const int row0 = m0 + wr * 128, col0 = n0 + wc * 64 + lr;
  #pragma unroll
  for (int m = 0; m < 8; m++)
    #pragma unroll
    for (int n = 0; n < 4; n++)
      #pragma unroll
      for (int r = 0; r < 4; r++){
        int row = row0 + m * 16 + kg * 4 + r;
        int col = col0 + n * 16;
        Cp[(size_t)row * ldc + col] = acc[m][n][r];
      }
}

// ---------------- reduce: dst16 = fp16(s0+s1+s2+s3), grid covers n/4 -------
__global__ __launch_bounds__(256) void reduce_t(u16* __restrict__ dst,
                                                const float* __restrict__ s0,
                                                const float* __restrict__ s1,
                                                const float* __restrict__ s2,
                                                const float* __restrict__ s3){
  int idx = blockIdx.x * 256 + threadIdx.x;
  float4 a = ((const float4*)s0)[idx];
  float4 b = ((const float4*)s1)[idx];
  float4 c = ((const float4*)s2)[idx];
  float4 d = ((const float4*)s3)[idx];
  ushort4 o;
  o.x = f2h((a.x + b.x) + (c.x + d.x));
  o.y = f2h((a.y + b.y) + (c.y + d.y));
  o.z = f2h((a.z + b.z) + (c.z + d.z));
  o.w = f2h((a.w + b.w) + (c.w + d.w));
  ((ushort4*)dst)[idx] = o;
}

// ---------------- reduce: out += hole1 + hole2 + slab3 ----------------
__global__ __launch_bounds__(256) void reduce_pv(float* __restrict__ out,
                                                 const float* __restrict__ Sf,
                                                 const float* __restrict__ s3){
  int idx = blockIdx.x * 256 + threadIdx.x;
  int r = idx >> 8, c4 = (idx & 255) * 4;
  float4 a = ((const float4*)out)[idx];
  float4 b = ((const float4*)s3)[idx];
  float4 h1 = *(const float4*)&Sf[(size_t)r * 4096 + 2048 + c4];
  float4 h2 = *(const float4*)&Sf[(size_t)r * 4096 + 3072 + c4];
  float4 o;
  o.x = (a.x + b.x) + (h1.x + h2.x);
  o.y = (a.y + b.y) + (h1.y + h2.y);
  o.z = (a.z + b.z) + (h1.z + h2.z);
  o.w = (a.w + b.w) + (h1.w + h2.w);
  ((float4*)out)[idx] = o;
}

// ---------------- softmax over rows of S (4096 fp32), write P fp16 in-place -
__global__ __launch_bounds__(256) void softmax_rows(float* __restrict__ S){
  int rrow = blockIdx.x;
  float* srow = S + (size_t)rrow * 4096;
  __shared__ float e[4096];
  __shared__ float red[4];
  int tid = threadIdx.x;

  float m = -1e30f;
  for (int i = tid * 4; i < 4096; i += 1024){
    float4 v = *(const float4*)(srow + i);
    m = fmaxf(m, fmaxf(fmaxf(v.x, v.y), fmaxf(v.z, v.w)));
  }
  for (int o = 32; o > 0; o >>= 1) m = fmaxf(m, __shfl_xor(m, o));
  if ((tid & 63) == 0) red[tid >> 6] = m;
  __syncthreads();
  m = fmaxf(fmaxf(red[0], red[1]), fmaxf(red[2], red[3]));

  float s = 0.f;
  for (int i = tid * 4; i < 4096; i += 1024){
    float4 v = *(const float4*)(srow + i);
    float4 ev;
    ev.x = __expf(v.x - m); ev.y = __expf(v.y - m);
    ev.z = __expf(v.z - m); ev.w = __expf(v.w - m);
    s += (ev.x + ev.y) + (ev.z + ev.w);
    *(float4*)&e[i] = ev;
  }
  for (int o = 32; o > 0; o >>= 1) s += __shfl_xor(s, o);
  __syncthreads();
  if ((tid & 63) == 0) red[tid >> 6] = s;
  __syncthreads();
  s = (red[0] + red[1]) + (red[2] + red[3]);

  float scale = 0.03125f / s;    // fold post-softmax 1/sqrt(dk)=1/32 into P
  u16* prow = (u16*)((char*)S + (size_t)rrow * 16384);
  for (int i = tid * 4; i < 4096; i += 1024){
    float4 v = *(const float4*)&e[i];
    ushort4 o; o.x = f2h(v.x * scale); o.y = f2h(v.y * scale);
    o.z = f2h(v.z * scale); o.w = f2h(v.w * scale);
    *(ushort4*)(prow + i) = o;
  }
}

extern "C" void kernel_launch(void* const* d_in, const int* in_sizes, int n_in,
                              void* d_out, int out_size, void* d_ws, size_t ws_size,
                              hipStream_t stream){
  const float* z  = (const float*)d_in[0];
  const float* Wq = (const float*)d_in[1];
  const float* Wk = (const float*)d_in[2];
  const float* Wv = (const float*)d_in[3];
  char* ws = (char*)d_ws;
  const size_t MB = 1ull << 20;

  // layout: 0-8 t16 | 8-16 z16 | 16-24 vt16 | 24-88 staging/S | 88-90 m16
  u16* t16   = (u16*)(ws + 0 * MB);
  u16* z16   = (u16*)(ws + 8 * MB);
  u16* vt16  = (u16*)(ws + 16 * MB);
  float* S   = (float*)(ws + 24 * MB);
  u16* m16   = (u16*)(ws + 88 * MB);
  float* slab3 = (float*)(ws + 0 * MB);           // PV partial (t16/z16 dead)
  // t partial slabs (24-88, written after z_hi/weights/wvt dead):
  float* ts0 = (float*)(ws + 24 * MB);
  float* ts1 = (float*)(ws + 40 * MB);
  float* ts2 = (float*)(ws + 56 * MB);
  float* ts3 = (float*)(ws + 72 * MB);
  // prep scratch:
  u16* z_hi  = (u16*)(ws + 24 * MB);              // dead before ts0
  u16* wqh   = (u16*)(ws + 32 * MB);
  u16* wql   = (u16*)(ws + 34 * MB);
  u16* wkh   = (u16*)(ws + 36 * MB);
  u16* wkl   = (u16*)(ws + 38 * MB);
  float* msl = (float*)(ws + 40 * MB);            // m' slabs 4x4MB (40-56)
  u16* wvt_h = (u16*)(ws + 56 * MB);              // dead before ts2

  split_z<<<4096, 256, 0, stream>>>(z, z_hi, z16, 4096 * 1024 / 4);
  split_f32<<<1024, 256, 0, stream>>>(Wq, wqh, wql, 1024 * 1024 / 4);
  split_f32<<<1024, 256, 0, stream>>>(Wk, wkh, wkl, 1024 * 1024 / 4);
  transpose_wv<<<dim3(16, 16), 256, 0, stream>>>(Wv, wvt_h);

  // m'[m,n] = sum_a Wk[m,a] Wq[n,a]  (split, split-K=4 -> fp32 slabs)
  gemm_bt<0, 0><<<dim3(8, 8, 4), 256, 0, stream>>>(wkh, wkl, 1024,
      wqh, wql, 1024, msl, 1024, 256, (size_t)1024 * 1024);
  reduce_t<<<1024, 256, 0, stream>>>(m16, msl, msl + 1048576,
      msl + 2097152, msl + 3145728);

  // v^T = Wv^T x z (bf16 single, fp16 out)  M=1024 N=4096 K=1024
  gemm_bt<1, 1><<<dim3(32, 8), 256, 0, stream>>>(wvt_h, nullptr, 1024,
      z_hi, nullptr, 1024, vt16, 4096, 1024, 0);

  // t = z16 @ m16^T (fp16 single, split-K=4 -> fp32 slabs; 1024 blocks)
  gemm_bt<2, 0><<<dim3(8, 32, 4), 256, 0, stream>>>(z16, nullptr, 1024,
      m16, nullptr, 1024, ts0, 1024, 256, (size_t)4096 * 1024);
  reduce_t<<<4096, 256, 0, stream>>>(t16, ts0, ts1, ts2, ts3);

  // S = t16 @ z16^T  fp32  M=N=4096 K=1024
  gemm256<<<dim3(16, 16, 1), 512, 0, stream>>>(t16, 1024, z16, 1024,
      S, 4096, S, 4096, S, 4096, S, 4096, 1024);

  // softmax rows -> P fp16 in-place (stride 8192 u16), 1/32 folded in
  softmax_rows<<<4096, 256, 0, stream>>>(S);

  // out = P @ v, split-K=4. partials: z0 -> d_out, z1/z2 -> holes, z3 -> slab3
  gemm256<<<dim3(4, 16, 4), 512, 0, stream>>>((u16*)S, 8192, vt16, 4096,
      (float*)d_out, 1024, S + 2048, 4096, S + 3072, 4096, slab3, 1024, 1024);

  // out += hole1 + hole2 + slab3
  reduce_pv<<<4096, 256, 0, stream>>>((float*)d_out, S, slab3);
}

// Round 14
// 176.167 us; speedup vs baseline: 1.2156x; 1.0900x over previous
//
#include <hip/hip_runtime.h>

typedef unsigned short u16;
typedef unsigned int u32;
typedef __attribute__((ext_vector_type(8))) short bf16x8;
typedef __attribute__((ext_vector_type(8))) _Float16 f16x8;
typedef __attribute__((ext_vector_type(4))) float f32x4;

__device__ inline u16 f2bf(float f){
  union { float f; unsigned u; } v; v.f = f;
  unsigned r = v.u + 0x7FFFu + ((v.u >> 16) & 1u);
  return (u16)(r >> 16);
}
__device__ inline float bf2f(u16 u){
  union { unsigned u; float f; } v; v.u = ((unsigned)u) << 16;
  return v.f;
}
__device__ inline u16 f2h(float f){
  union { _Float16 h; u16 u; } v; v.h = (_Float16)f; return v.u;
}

// async 16B/lane global->LDS. lds dest is wave-uniform base + lane*16 (HW).
__device__ inline void gload16(const u16* g, u16* l){
  __builtin_amdgcn_global_load_lds(
      (const __attribute__((address_space(1))) u32*)(const void*)g,
      (__attribute__((address_space(3))) u32*)(void*)l, 16, 0, 0);
}

#define WAITV(n) asm volatile("s_waitcnt vmcnt(" #n ")" ::: "memory")
#define FENCE()  asm volatile("" ::: "memory")

// ---------------- prep: split fp32 -> bf16 hi/lo (weights) ----------------
__global__ __launch_bounds__(256) void split_f32(const float* __restrict__ x,
                                                 u16* __restrict__ hi,
                                                 u16* __restrict__ lo, int n4){
  int i = blockIdx.x * 256 + threadIdx.x;
  if (i >= n4) return;
  float4 v = ((const float4*)x)[i];
  float a0 = v.x, a1 = v.y, a2 = v.z, a3 = v.w;
  u16 h0 = f2bf(a0), h1 = f2bf(a1), h2 = f2bf(a2), h3 = f2bf(a3);
  ushort4 h; h.x = h0; h.y = h1; h.z = h2; h.w = h3;
  ushort4 l; l.x = f2bf(a0 - bf2f(h0)); l.y = f2bf(a1 - bf2f(h1));
  l.z = f2bf(a2 - bf2f(h2)); l.w = f2bf(a3 - bf2f(h3));
  ((ushort4*)hi)[i] = h;
  ((ushort4*)lo)[i] = l;
}

// ---------------- prep: z -> fp16 copy only ----------------
__global__ __launch_bounds__(256) void conv_h16(const float* __restrict__ x,
                                                u16* __restrict__ h16, int n4){
  int i = blockIdx.x * 256 + threadIdx.x;
  if (i >= n4) return;
  float4 v = ((const float4*)x)[i];
  ushort4 g; g.x = f2h(v.x); g.y = f2h(v.y); g.z = f2h(v.z); g.w = f2h(v.w);
  ((ushort4*)h16)[i] = g;
}

// ---------------- prep: transpose Wv -> fp16 ----------------
__global__ __launch_bounds__(256) void transpose_wv16(
    const float* __restrict__ W, u16* __restrict__ H){
  __shared__ float t[64][65];
  int d0 = blockIdx.y * 64, n0 = blockIdx.x * 64;
  int tid = threadIdx.x;
  int r = tid >> 4, c4 = (tid & 15) * 4;
  for (int rr = r; rr < 64; rr += 16){
    float4 v = *(const float4*)&W[(size_t)(d0 + rr) * 1024 + n0 + c4];
    t[rr][c4 + 0] = v.x; t[rr][c4 + 1] = v.y; t[rr][c4 + 2] = v.z; t[rr][c4 + 3] = v.w;
  }
  __syncthreads();
  int n = tid >> 4, d4 = (tid & 15) * 4;
  for (int nn = n; nn < 64; nn += 16){
    ushort4 h;
    h.x = f2h(t[d4 + 0][nn]); h.y = f2h(t[d4 + 1][nn]);
    h.z = f2h(t[d4 + 2][nn]); h.w = f2h(t[d4 + 3][nn]);
    *(ushort4*)&H[(size_t)(n0 + nn) * 1024 + d0 + d4] = h;
  }
}

// ---------------- small GEMM (128x128 tile, 4 waves) ----------------
// IN: 0 = bf16 split (hi/lo, 3-MFMA chain), 2 = fp16 single.
// EPI: 0 = fp32 out into slab blockIdx.z*zslab; 1 = fp16 out.
// Split-K via blockIdx.z: operands offset by z*K columns.
template<int IN, int EPI>
__global__ __launch_bounds__(256) void gemm_bt(
    const u16* __restrict__ Ah, const u16* __restrict__ Al, int lda,
    const u16* __restrict__ Bh, const u16* __restrict__ Bl, int ldb,
    void* __restrict__ C0, int ldc, int K, size_t zslab){
  constexpr int NPL = (IN == 0) ? 4 : 2;
  constexpr int DEPTH = (IN == 0) ? 1 : 2;
  constexpr int NBUF = DEPTH + 1;
  __shared__ __align__(16) u16 sm[NBUF * NPL * 4096];

  const int kz = blockIdx.z * K;
  Ah += kz; Bh += kz;
  if constexpr (IN == 0){ Al += kz; Bl += kz; }

  const int tid = threadIdx.x;
  const int lane = tid & 63, wave = tid >> 6;
  const int wr = wave >> 1, wc = wave & 1;
  const int lr = lane & 15, kg = lane >> 4;

  const int nwg = gridDim.x * gridDim.y;
  const int id = blockIdx.y * gridDim.x + blockIdx.x;
  const int chunk = nwg >> 3;
  const int swz = (id & 7) * chunk + (id >> 3);
  const int bx = swz % gridDim.x, by = swz / gridDim.x;
  const int m0 = by * 128, n0 = bx * 128;

  const int l_r = lane >> 2, l_c = lane & 3;
  const int st_chunk = l_c ^ ((l_r + (l_r >> 2)) & 3);
  const int rd_swz = (lr + (lr >> 2)) & 3;

  f32x4 acc[4][4];
  #pragma unroll
  for (int m = 0; m < 4; m++)
    #pragma unroll
    for (int n = 0; n < 4; n++)
      acc[m][n] = (f32x4){0.f, 0.f, 0.f, 0.f};

  auto STAGE = [&](int buf, int k0){
    #pragma unroll
    for (int c = 0; c < NPL * 2; ++c){
      int pc = c * 4 + wave;
      int p = pc >> 3, ch = pc & 7;
      const u16* g; int ld, rb;
      if (IN == 0){
        g = (p == 0) ? Ah : (p == 1) ? Al : (p == 2) ? Bh : Bl;
        ld = (p < 2) ? lda : ldb;  rb = (p < 2) ? m0 : n0;
      } else {
        g = (p == 0) ? Ah : Bh;
        ld = (p == 0) ? lda : ldb; rb = (p == 0) ? m0 : n0;
      }
      int r = ch * 16 + l_r;
      const u16* src = g + (size_t)(rb + r) * ld + k0 + st_chunk * 8;
      u16* dst = &sm[((size_t)buf * NPL + p) * 4096 + ch * 512];
      gload16(src, dst);
    }
  };

  const int KT = K >> 5;
  STAGE(0, 0);
  if constexpr (DEPTH == 2){ if (KT > 1) STAGE(1, 32); }

  int bufc = 0, pfb = DEPTH % NBUF;
  for (int kt = 0; kt < KT; ++kt){
    const int pf = kt + DEPTH;
    if (pf < KT){
      STAGE(pfb, pf * 32);
      WAITV(8);
    } else if (kt + 1 < KT){
      if constexpr (IN == 0) WAITV(8); else WAITV(4);
    } else {
      WAITV(0);
    }
    __builtin_amdgcn_s_barrier();
    FENCE();

    const u16* pA  = &sm[((size_t)bufc * NPL + 0) * 4096];
    const u16* pAl = &sm[((size_t)bufc * NPL + 1) * 4096];
    const u16* pB  = &sm[((size_t)bufc * NPL + (IN == 0 ? 2 : 1)) * 4096];
    const u16* pBl = &sm[((size_t)bufc * NPL + 3) * 4096];

    const int slot = (kg ^ rd_swz) * 8;
    bf16x8 afh[4], bfh[4], afl[4], bfl[4];
    f16x8 ah16[4], bh16[4];
    #pragma unroll
    for (int m = 0; m < 4; m++){
      int r = wr * 64 + m * 16 + lr;
      if (IN == 2) ah16[m] = *(const f16x8*)&pA[r * 32 + slot];
      else {
        afh[m] = *(const bf16x8*)&pA[r * 32 + slot];
        if (IN == 0) afl[m] = *(const bf16x8*)&pAl[r * 32 + slot];
      }
    }
    #pragma unroll
    for (int n = 0; n < 4; n++){
      int r = wc * 64 + n * 16 + lr;
      if (IN == 2) bh16[n] = *(const f16x8*)&pB[r * 32 + slot];
      else {
        bfh[n] = *(const bf16x8*)&pB[r * 32 + slot];
        if (IN == 0) bfl[n] = *(const bf16x8*)&pBl[r * 32 + slot];
      }
    }
    #pragma unroll
    for (int m = 0; m < 4; m++)
      #pragma unroll
      for (int n = 0; n < 4; n++){
        if (IN == 2){
          acc[m][n] = __builtin_amdgcn_mfma_f32_16x16x32_f16(ah16[m], bh16[n], acc[m][n], 0, 0, 0);
        } else {
          acc[m][n] = __builtin_amdgcn_mfma_f32_16x16x32_bf16(afh[m], bfh[n], acc[m][n], 0, 0, 0);
          if (IN == 0){
            acc[m][n] = __builtin_amdgcn_mfma_f32_16x16x32_bf16(afl[m], bfh[n], acc[m][n], 0, 0, 0);
            acc[m][n] = __builtin_amdgcn_mfma_f32_16x16x32_bf16(afh[m], bfl[n], acc[m][n], 0, 0, 0);
          }
        }
      }
    FENCE();
    __builtin_amdgcn_s_barrier();
    bufc = (bufc + 1 == NBUF) ? 0 : bufc + 1;
    pfb  = (pfb  + 1 == NBUF) ? 0 : pfb  + 1;
  }

  const int row0 = m0 + wr * 64, col0 = n0 + wc * 64 + lr;
  #pragma unroll
  for (int m = 0; m < 4; m++)
    #pragma unroll
    for (int n = 0; n < 4; n++)
      #pragma unroll
      for (int r = 0; r < 4; r++){
        int row = row0 + m * 16 + kg * 4 + r;
        int col = col0 + n * 16;
        float x = acc[m][n][r];
        if (EPI == 0){
          float* C = (float*)C0 + (size_t)blockIdx.z * zslab;
          C[(size_t)row * ldc + col] = x;
        } else {
          ((u16*)C0)[(size_t)row * ldc + col] = f2h(x);
        }
      }
}

// ---------------- big GEMM: 256x256 tile, BK=64, 8 waves, wave 128x64 ------
// fp16 in, fp32 out. (R11 schedule: best measured, 771 TF.) LDS 128KB =
// 2 bufs x (A 32KB + B 32KB). 8-slot XOR involution swizzle for 128B rows,
// zero bank conflicts (verified R11). One vmcnt(0)+barrier per K-tile.
__global__ __launch_bounds__(512, 1) void gemm256(
    const u16* __restrict__ A, int lda,
    const u16* __restrict__ B, int ldb,
    float* __restrict__ C0z, int l0, float* __restrict__ C1z, int l1,
    float* __restrict__ C2z, int l2, float* __restrict__ C3z, int l3,
    int K){
  __shared__ __align__(16) u16 sm[2 * 32768];

  const int tid = threadIdx.x;
  const int lane = tid & 63, wave = tid >> 6;
  const int wr = wave >> 2, wc = wave & 3;        // 2 x 4 waves
  const int lr = lane & 15, kg = lane >> 4;
  const int g7 = lr & 7;

  const int nwg = gridDim.x * gridDim.y;
  const int id = blockIdx.y * gridDim.x + blockIdx.x;
  const int chunk = nwg >> 3;
  const int swz = (id & 7) * chunk + (id >> 3);
  const int bx = swz % gridDim.x, by = swz / gridDim.x;
  const int m0 = by * 256, n0 = bx * 256;

  A += (size_t)blockIdx.z * (size_t)K;
  B += (size_t)blockIdx.z * (size_t)K;
  float* Cp; int ldc;
  if (blockIdx.z == 0){ Cp = C0z; ldc = l0; }
  else if (blockIdx.z == 1){ Cp = C1z; ldc = l1; }
  else if (blockIdx.z == 2){ Cp = C2z; ldc = l2; }
  else { Cp = C3z; ldc = l3; }

  auto STAGE = [&](int buf, int k0){
    #pragma unroll
    for (int rd = 0; rd < 8; ++rd){
      int p = rd >> 2;
      int r0 = (rd & 3) * 64 + wave * 8;
      const u16* g = p ? B : A;
      int ld = p ? ldb : lda;
      int rb = p ? n0 : m0;
      int grow = rb + r0 + (lane >> 3);
      int gch = (lane & 7) ^ (lane >> 3);
      const u16* src = g + (size_t)grow * ld + k0 + gch * 8;
      u16* dst = &sm[(size_t)buf * 32768 + p * 16384 + r0 * 64];
      gload16(src, dst);
    }
  };

  f32x4 acc[8][4];
  #pragma unroll
  for (int m = 0; m < 8; m++)
    #pragma unroll
    for (int n = 0; n < 4; n++)
      acc[m][n] = (f32x4){0.f, 0.f, 0.f, 0.f};

  const int KT = K >> 6;
  STAGE(0, 0);

  int bufc = 0;
  for (int kt = 0; kt < KT; ++kt){
    WAITV(0);
    __builtin_amdgcn_s_barrier();
    FENCE();
    if (kt + 1 < KT) STAGE(bufc ^ 1, (kt + 1) * 64);

    const u16* pA = &sm[(size_t)bufc * 32768];
    const u16* pB = pA + 16384;
    #pragma unroll
    for (int ks = 0; ks < 2; ++ks){
      f16x8 b[4], a[8];
      #pragma unroll
      for (int n = 0; n < 4; n++){
        int R = wc * 64 + n * 16 + lr;
        b[n] = *(const f16x8*)&pB[R * 64 + (((ks * 4 + kg) ^ g7) * 8)];
      }
      #pragma unroll
      for (int m = 0; m < 8; m++){
        int R = wr * 128 + m * 16 + lr;
        a[m] = *(const f16x8*)&pA[R * 64 + (((ks * 4 + kg) ^ g7) * 8)];
      }
      __builtin_amdgcn_s_setprio(1);
      #pragma unroll
      for (int m = 0; m < 8; m++)
        #pragma unroll
        for (int n = 0; n < 4; n++)
          acc[m][n] = __builtin_amdgcn_mfma_f32_16x16x32_f16(a[m], b[n], acc[m][n], 0, 0, 0);
      __builtin_amdgcn_s_setprio(0);
    }
    FENCE();
    bufc ^= 1;
  }

  const int row0 = m0 + wr * 128, col0 = n0 + wc * 64 + lr;
  #pragma unroll
  for (int m = 0; m < 8; m++)
    #pragma unroll
    for (int n = 0; n < 4; n++)
      #pragma unroll
      for (int r = 0; r < 4; r++){
        int row = row0 + m * 16 + kg * 4 + r;
        int col = col0 + n * 16;
        Cp[(size_t)row * ldc + col] = acc[m][n][r];
      }
}

// ---------------- reduce: dst16 = fp16(s0+s1+s2+s3) ----------------
__global__ __launch_bounds__(256) void reduce_t(u16* __restrict__ dst,
                                                const float* __restrict__ s0,
                                                const float* __restrict__ s1,
                                                const float* __restrict__ s2,
                                                const float* __restrict__ s3){
  int idx = blockIdx.x * 256 + threadIdx.x;
  float4 a = ((const float4*)s0)[idx];
  float4 b = ((const float4*)s1)[idx];
  float4 c = ((const float4*)s2)[idx];
  float4 d = ((const float4*)s3)[idx];
  ushort4 o;
  o.x = f2h((a.x + b.x) + (c.x + d.x));
  o.y = f2h((a.y + b.y) + (c.y + d.y));
  o.z = f2h((a.z + b.z) + (c.z + d.z));
  o.w = f2h((a.w + b.w) + (c.w + d.w));
  ((ushort4*)dst)[idx] = o;
}

// ---------------- reduce: out += hole1 + hole2 + slab3 ----------------
__global__ __launch_bounds__(256) void reduce_pv(float* __restrict__ out,
                                                 const float* __restrict__ Sf,
                                                 const float* __restrict__ s3){
  int idx = blockIdx.x * 256 + threadIdx.x;
  int r = idx >> 8, c4 = (idx & 255) * 4;
  float4 a = ((const float4*)out)[idx];
  float4 b = ((const float4*)s3)[idx];
  float4 h1 = *(const float4*)&Sf[(size_t)r * 4096 + 2048 + c4];
  float4 h2 = *(const float4*)&Sf[(size_t)r * 4096 + 3072 + c4];
  float4 o;
  o.x = (a.x + b.x) + (h1.x + h2.x);
  o.y = (a.y + b.y) + (h1.y + h2.y);
  o.z = (a.z + b.z) + (h1.z + h2.z);
  o.w = (a.w + b.w) + (h1.w + h2.w);
  ((float4*)out)[idx] = o;
}

// ---------------- softmax over rows of S (4096 fp32), write P fp16 in-place -
__global__ __launch_bounds__(256) void softmax_rows(float* __restrict__ S){
  int rrow = blockIdx.x;
  float* srow = S + (size_t)rrow * 4096;
  __shared__ float e[4096];
  __shared__ float red[4];
  int tid = threadIdx.x;

  float m = -1e30f;
  for (int i = tid * 4; i < 4096; i += 1024){
    float4 v = *(const float4*)(srow + i);
    m = fmaxf(m, fmaxf(fmaxf(v.x, v.y), fmaxf(v.z, v.w)));
  }
  for (int o = 32; o > 0; o >>= 1) m = fmaxf(m, __shfl_xor(m, o));
  if ((tid & 63) == 0) red[tid >> 6] = m;
  __syncthreads();
  m = fmaxf(fmaxf(red[0], red[1]), fmaxf(red[2], red[3]));

  float s = 0.f;
  for (int i = tid * 4; i < 4096; i += 1024){
    float4 v = *(const float4*)(srow + i);
    float4 ev;
    ev.x = __expf(v.x - m); ev.y = __expf(v.y - m);
    ev.z = __expf(v.z - m); ev.w = __expf(v.w - m);
    s += (ev.x + ev.y) + (ev.z + ev.w);
    *(float4*)&e[i] = ev;
  }
  for (int o = 32; o > 0; o >>= 1) s += __shfl_xor(s, o);
  __syncthreads();
  if ((tid & 63) == 0) red[tid >> 6] = s;
  __syncthreads();
  s = (red[0] + red[1]) + (red[2] + red[3]);

  float scale = 0.03125f / s;    // fold post-softmax 1/sqrt(dk)=1/32 into P
  u16* prow = (u16*)((char*)S + (size_t)rrow * 16384);
  for (int i = tid * 4; i < 4096; i += 1024){
    float4 v = *(const float4*)&e[i];
    ushort4 o; o.x = f2h(v.x * scale); o.y = f2h(v.y * scale);
    o.z = f2h(v.z * scale); o.w = f2h(v.w * scale);
    *(ushort4*)(prow + i) = o;
  }
}

extern "C" void kernel_launch(void* const* d_in, const int* in_sizes, int n_in,
                              void* d_out, int out_size, void* d_ws, size_t ws_size,
                              hipStream_t stream){
  const float* z  = (const float*)d_in[0];
  const float* Wq = (const float*)d_in[1];
  const float* Wk = (const float*)d_in[2];
  const float* Wv = (const float*)d_in[3];
  char* ws = (char*)d_ws;
  const size_t MB = 1ull << 20;

  // layout: 0-8 t16 | 8-16 z16 | 16-24 vt16 | 24-88 prep/S | 88-90 m16
  u16* t16   = (u16*)(ws + 0 * MB);
  u16* z16   = (u16*)(ws + 8 * MB);
  u16* vt16  = (u16*)(ws + 16 * MB);
  float* S   = (float*)(ws + 24 * MB);
  u16* m16   = (u16*)(ws + 88 * MB);
  float* slab3 = (float*)(ws + 0 * MB);           // PV partial (t16/z16 dead)
  // prep scratch (24-88, all dead before S is written):
  u16* wqh   = (u16*)(ws + 24 * MB);
  u16* wql   = (u16*)(ws + 26 * MB);
  u16* wkh   = (u16*)(ws + 28 * MB);
  u16* wkl   = (u16*)(ws + 30 * MB);
  u16* wvt16 = (u16*)(ws + 32 * MB);
  float* msl = (float*)(ws + 40 * MB);            // m' slabs 4x4MB (40-56)

  conv_h16<<<4096, 256, 0, stream>>>(z, z16, 4096 * 1024 / 4);
  split_f32<<<1024, 256, 0, stream>>>(Wq, wqh, wql, 1024 * 1024 / 4);
  split_f32<<<1024, 256, 0, stream>>>(Wk, wkh, wkl, 1024 * 1024 / 4);
  transpose_wv16<<<dim3(16, 16), 256, 0, stream>>>(Wv, wvt16);

  // m'[m,n] = sum_a Wk[m,a] Wq[n,a]  (split, split-K=4 -> fp32 slabs)
  gemm_bt<0, 0><<<dim3(8, 8, 4), 256, 0, stream>>>(wkh, wkl, 1024,
      wqh, wql, 1024, msl, 1024, 256, (size_t)1024 * 1024);
  reduce_t<<<1024, 256, 0, stream>>>(m16, msl, msl + 1048576,
      msl + 2097152, msl + 3145728);

  // v^T = Wv^T x z (fp16 single, fp16 out)  M=1024 N=4096 K=1024
  gemm_bt<2, 1><<<dim3(32, 8), 256, 0, stream>>>(wvt16, nullptr, 1024,
      z16, nullptr, 1024, vt16, 4096, 1024, 0);

  // t = z16 @ m16^T (fp16 single, fp16 out, no split-K)  M=4096 N=1024
  gemm_bt<2, 1><<<dim3(8, 32), 256, 0, stream>>>(z16, nullptr, 1024,
      m16, nullptr, 1024, t16, 1024, 1024, 0);

  // S = t16 @ z16^T  fp32  M=N=4096 K=1024
  gemm256<<<dim3(16, 16, 1), 512, 0, stream>>>(t16, 1024, z16, 1024,
      S, 4096, S, 4096, S, 4096, S, 4096, 1024);

  // softmax rows -> P fp16 in-place (stride 8192 u16), 1/32 folded in
  softmax_rows<<<4096, 256, 0, stream>>>(S);

  // out = P @ v, split-K=4. partials: z0 -> d_out, z1/z2 -> holes, z3 -> slab3
  gemm256<<<dim3(4, 16, 4), 512, 0, stream>>>((u16*)S, 8192, vt16, 4096,
      (float*)d_out, 1024, S + 2048, 4096, S + 3072, 4096, slab3, 1024, 1024);

  // out += hole1 + hole2 + slab3
  reduce_pv<<<4096, 256, 0, stream>>>((float*)d_out, S, slab3);
}

// Round 15
// 158.660 us; speedup vs baseline: 1.3498x; 1.1103x over previous
//
#include <hip/hip_runtime.h>

typedef unsigned short u16;
typedef unsigned int u32;
typedef __attribute__((ext_vector_type(8))) short bf16x8;
typedef __attribute__((ext_vector_type(8))) _Float16 f16x8;
typedef __attribute__((ext_vector_type(4))) float f32x4;

__device__ inline u16 f2bf(float f){
  union { float f; unsigned u; } v; v.f = f;
  unsigned r = v.u + 0x7FFFu + ((v.u >> 16) & 1u);
  return (u16)(r >> 16);
}
__device__ inline float bf2f(u16 u){
  union { unsigned u; float f; } v; v.u = ((unsigned)u) << 16;
  return v.f;
}
__device__ inline u16 f2h(float f){
  union { _Float16 h; u16 u; } v; v.h = (_Float16)f; return v.u;
}

// async 16B/lane global->LDS. lds dest is wave-uniform base + lane*16 (HW).
__device__ inline void gload16(const u16* g, u16* l){
  __builtin_amdgcn_global_load_lds(
      (const __attribute__((address_space(1))) u32*)(const void*)g,
      (__attribute__((address_space(3))) u32*)(void*)l, 16, 0, 0);
}

#define WAITV(n) asm volatile("s_waitcnt vmcnt(" #n ")" ::: "memory")
#define FENCE()  asm volatile("" ::: "memory")

// ---------------- prep: split Wq+Wk fp32 -> bf16 hi/lo (one launch) --------
__global__ __launch_bounds__(256) void split_wqk(const float* __restrict__ wq,
                                                 const float* __restrict__ wk,
                                                 u16* __restrict__ qh, u16* __restrict__ ql,
                                                 u16* __restrict__ kh, u16* __restrict__ kl){
  int b = blockIdx.x;
  const float* x; u16 *hi, *lo;
  int i;
  if (b < 1024){ x = wq; hi = qh; lo = ql; i = b * 256 + threadIdx.x; }
  else         { x = wk; hi = kh; lo = kl; i = (b - 1024) * 256 + threadIdx.x; }
  float4 v = ((const float4*)x)[i];
  float a0 = v.x, a1 = v.y, a2 = v.z, a3 = v.w;
  u16 h0 = f2bf(a0), h1 = f2bf(a1), h2 = f2bf(a2), h3 = f2bf(a3);
  ushort4 h; h.x = h0; h.y = h1; h.z = h2; h.w = h3;
  ushort4 l; l.x = f2bf(a0 - bf2f(h0)); l.y = f2bf(a1 - bf2f(h1));
  l.z = f2bf(a2 - bf2f(h2)); l.w = f2bf(a3 - bf2f(h3));
  ((ushort4*)hi)[i] = h;
  ((ushort4*)lo)[i] = l;
}

// ---------------- prep: z -> fp16 copy ----------------
__global__ __launch_bounds__(256) void conv_h16(const float* __restrict__ x,
                                                u16* __restrict__ h16, int n4){
  int i = blockIdx.x * 256 + threadIdx.x;
  if (i >= n4) return;
  float4 v = ((const float4*)x)[i];
  ushort4 g; g.x = f2h(v.x); g.y = f2h(v.y); g.z = f2h(v.z); g.w = f2h(v.w);
  ((ushort4*)h16)[i] = g;
}

// ---------------- prep: transpose Wv -> fp16 ----------------
__global__ __launch_bounds__(256) void transpose_wv16(
    const float* __restrict__ W, u16* __restrict__ H){
  __shared__ float t[64][65];
  int d0 = blockIdx.y * 64, n0 = blockIdx.x * 64;
  int tid = threadIdx.x;
  int r = tid >> 4, c4 = (tid & 15) * 4;
  for (int rr = r; rr < 64; rr += 16){
    float4 v = *(const float4*)&W[(size_t)(d0 + rr) * 1024 + n0 + c4];
    t[rr][c4 + 0] = v.x; t[rr][c4 + 1] = v.y; t[rr][c4 + 2] = v.z; t[rr][c4 + 3] = v.w;
  }
  __syncthreads();
  int n = tid >> 4, d4 = (tid & 15) * 4;
  for (int nn = n; nn < 64; nn += 16){
    ushort4 h;
    h.x = f2h(t[d4 + 0][nn]); h.y = f2h(t[d4 + 1][nn]);
    h.z = f2h(t[d4 + 2][nn]); h.w = f2h(t[d4 + 3][nn]);
    *(ushort4*)&H[(size_t)(n0 + nn) * 1024 + d0 + d4] = h;
  }
}

// ---------------- small GEMM (128x128 tile, 4 waves): m' only --------------
// IN=0: bf16 split (hi/lo, 3-MFMA chain). EPI=0: fp32 slab out (split-K).
template<int IN, int EPI>
__global__ __launch_bounds__(256) void gemm_bt(
    const u16* __restrict__ Ah, const u16* __restrict__ Al, int lda,
    const u16* __restrict__ Bh, const u16* __restrict__ Bl, int ldb,
    void* __restrict__ C0, int ldc, int K, size_t zslab){
  constexpr int NPL = 4;
  constexpr int DEPTH = 1;
  constexpr int NBUF = DEPTH + 1;
  __shared__ __align__(16) u16 sm[NBUF * NPL * 4096];

  const int kz = blockIdx.z * K;
  Ah += kz; Bh += kz; Al += kz; Bl += kz;

  const int tid = threadIdx.x;
  const int lane = tid & 63, wave = tid >> 6;
  const int wr = wave >> 1, wc = wave & 1;
  const int lr = lane & 15, kg = lane >> 4;

  const int nwg = gridDim.x * gridDim.y;
  const int id = blockIdx.y * gridDim.x + blockIdx.x;
  const int chunk = nwg >> 3;
  const int swz = (id & 7) * chunk + (id >> 3);
  const int bx = swz % gridDim.x, by = swz / gridDim.x;
  const int m0 = by * 128, n0 = bx * 128;

  const int l_r = lane >> 2, l_c = lane & 3;
  const int st_chunk = l_c ^ ((l_r + (l_r >> 2)) & 3);
  const int rd_swz = (lr + (lr >> 2)) & 3;

  f32x4 acc[4][4];
  #pragma unroll
  for (int m = 0; m < 4; m++)
    #pragma unroll
    for (int n = 0; n < 4; n++)
      acc[m][n] = (f32x4){0.f, 0.f, 0.f, 0.f};

  auto STAGE = [&](int buf, int k0){
    #pragma unroll
    for (int c = 0; c < NPL * 2; ++c){
      int pc = c * 4 + wave;
      int p = pc >> 3, ch = pc & 7;
      const u16* g = (p == 0) ? Ah : (p == 1) ? Al : (p == 2) ? Bh : Bl;
      int ld = (p < 2) ? lda : ldb;
      int rb = (p < 2) ? m0 : n0;
      int r = ch * 16 + l_r;
      const u16* src = g + (size_t)(rb + r) * ld + k0 + st_chunk * 8;
      u16* dst = &sm[((size_t)buf * NPL + p) * 4096 + ch * 512];
      gload16(src, dst);
    }
  };

  const int KT = K >> 5;
  STAGE(0, 0);

  int bufc = 0, pfb = DEPTH % NBUF;
  for (int kt = 0; kt < KT; ++kt){
    const int pf = kt + DEPTH;
    if (pf < KT){
      STAGE(pfb, pf * 32);
      WAITV(8);
    } else {
      WAITV(0);
    }
    __builtin_amdgcn_s_barrier();
    FENCE();

    const u16* pA  = &sm[((size_t)bufc * NPL + 0) * 4096];
    const u16* pAl = &sm[((size_t)bufc * NPL + 1) * 4096];
    const u16* pB  = &sm[((size_t)bufc * NPL + 2) * 4096];
    const u16* pBl = &sm[((size_t)bufc * NPL + 3) * 4096];

    const int slot = (kg ^ rd_swz) * 8;
    bf16x8 afh[4], bfh[4], afl[4], bfl[4];
    #pragma unroll
    for (int m = 0; m < 4; m++){
      int r = wr * 64 + m * 16 + lr;
      afh[m] = *(const bf16x8*)&pA[r * 32 + slot];
      afl[m] = *(const bf16x8*)&pAl[r * 32 + slot];
    }
    #pragma unroll
    for (int n = 0; n < 4; n++){
      int r = wc * 64 + n * 16 + lr;
      bfh[n] = *(const bf16x8*)&pB[r * 32 + slot];
      bfl[n] = *(const bf16x8*)&pBl[r * 32 + slot];
    }
    #pragma unroll
    for (int m = 0; m < 4; m++)
      #pragma unroll
      for (int n = 0; n < 4; n++){
        acc[m][n] = __builtin_amdgcn_mfma_f32_16x16x32_bf16(afh[m], bfh[n], acc[m][n], 0, 0, 0);
        acc[m][n] = __builtin_amdgcn_mfma_f32_16x16x32_bf16(afl[m], bfh[n], acc[m][n], 0, 0, 0);
        acc[m][n] = __builtin_amdgcn_mfma_f32_16x16x32_bf16(afh[m], bfl[n], acc[m][n], 0, 0, 0);
      }
    FENCE();
    __builtin_amdgcn_s_barrier();
    bufc = (bufc + 1 == NBUF) ? 0 : bufc + 1;
    pfb  = (pfb  + 1 == NBUF) ? 0 : pfb  + 1;
  }

  const int row0 = m0 + wr * 64, col0 = n0 + wc * 64 + lr;
  float* C = (float*)C0 + (size_t)blockIdx.z * zslab;
  #pragma unroll
  for (int m = 0; m < 4; m++)
    #pragma unroll
    for (int n = 0; n < 4; n++)
      #pragma unroll
      for (int r = 0; r < 4; r++){
        int row = row0 + m * 16 + kg * 4 + r;
        int col = col0 + n * 16;
        C[(size_t)row * ldc + col] = acc[m][n][r];
      }
}

// ---------------- dual GEMM: t (z@m'^T) || v^T (Wv^T@z^T) in one launch ----
// fp16 in/out, 128x128 tile, 4 waves, DEPTH=2 (triple buffer). Flat grid 512:
// blocks 0-255 -> problem 0 (t, gx=8), 256-511 -> problem 1 (v^T, gx=32).
// 2 blocks/CU co-resident -> m114 MFMA/mem overlap across blocks.
__global__ __launch_bounds__(256) void gemm_dual(
    const u16* __restrict__ A0, int lda0, const u16* __restrict__ B0, int ldb0,
    u16* __restrict__ C0_, int ldc0, int gx0,
    const u16* __restrict__ A1, int lda1, const u16* __restrict__ B1, int ldb1,
    u16* __restrict__ C1_, int ldc1, int gx1, int K){
  constexpr int NPL = 2, DEPTH = 2, NBUF = 3;
  __shared__ __align__(16) u16 sm[NBUF * NPL * 4096];

  const int id = blockIdx.x;
  const int l = id & 255;
  const int swz = (l & 7) * 32 + (l >> 3);          // XCD swizzle in half-grid
  const u16* Ah; const u16* Bh; u16* C; int lda, ldb, ldc, gx;
  if (id < 256){ Ah = A0; Bh = B0; C = C0_; lda = lda0; ldb = ldb0; ldc = ldc0; gx = gx0; }
  else         { Ah = A1; Bh = B1; C = C1_; lda = lda1; ldb = ldb1; ldc = ldc1; gx = gx1; }
  const int bx = swz % gx, by = swz / gx;
  const int m0 = by * 128, n0 = bx * 128;

  const int tid = threadIdx.x;
  const int lane = tid & 63, wave = tid >> 6;
  const int wr = wave >> 1, wc = wave & 1;
  const int lr = lane & 15, kg = lane >> 4;
  const int l_r = lane >> 2, l_c = lane & 3;
  const int st_chunk = l_c ^ ((l_r + (l_r >> 2)) & 3);
  const int rd_swz = (lr + (lr >> 2)) & 3;

  f32x4 acc[4][4];
  #pragma unroll
  for (int m = 0; m < 4; m++)
    #pragma unroll
    for (int n = 0; n < 4; n++)
      acc[m][n] = (f32x4){0.f, 0.f, 0.f, 0.f};

  auto STAGE = [&](int buf, int k0){
    #pragma unroll
    for (int c = 0; c < NPL * 2; ++c){
      int pc = c * 4 + wave;
      int p = pc >> 3, ch = pc & 7;
      const u16* g = (p == 0) ? Ah : Bh;
      int ld = (p == 0) ? lda : ldb;
      int rb = (p == 0) ? m0 : n0;
      int r = ch * 16 + l_r;
      const u16* src = g + (size_t)(rb + r) * ld + k0 + st_chunk * 8;
      u16* dst = &sm[((size_t)buf * NPL + p) * 4096 + ch * 512];
      gload16(src, dst);
    }
  };

  const int KT = K >> 5;
  STAGE(0, 0);
  if (KT > 1) STAGE(1, 32);

  int bufc = 0, pfb = DEPTH % NBUF;
  for (int kt = 0; kt < KT; ++kt){
    const int pf = kt + DEPTH;
    if (pf < KT){
      STAGE(pfb, pf * 32);
      WAITV(8);
    } else if (kt + 1 < KT){
      WAITV(4);
    } else {
      WAITV(0);
    }
    __builtin_amdgcn_s_barrier();
    FENCE();

    const u16* pA = &sm[((size_t)bufc * NPL + 0) * 4096];
    const u16* pB = &sm[((size_t)bufc * NPL + 1) * 4096];

    const int slot = (kg ^ rd_swz) * 8;
    f16x8 ah[4], bh[4];
    #pragma unroll
    for (int m = 0; m < 4; m++){
      int r = wr * 64 + m * 16 + lr;
      ah[m] = *(const f16x8*)&pA[r * 32 + slot];
    }
    #pragma unroll
    for (int n = 0; n < 4; n++){
      int r = wc * 64 + n * 16 + lr;
      bh[n] = *(const f16x8*)&pB[r * 32 + slot];
    }
    #pragma unroll
    for (int m = 0; m < 4; m++)
      #pragma unroll
      for (int n = 0; n < 4; n++)
        acc[m][n] = __builtin_amdgcn_mfma_f32_16x16x32_f16(ah[m], bh[n], acc[m][n], 0, 0, 0);
    FENCE();
    __builtin_amdgcn_s_barrier();
    bufc = (bufc + 1 == NBUF) ? 0 : bufc + 1;
    pfb  = (pfb  + 1 == NBUF) ? 0 : pfb  + 1;
  }

  const int row0 = m0 + wr * 64, col0 = n0 + wc * 64 + lr;
  #pragma unroll
  for (int m = 0; m < 4; m++)
    #pragma unroll
    for (int n = 0; n < 4; n++)
      #pragma unroll
      for (int r = 0; r < 4; r++){
        int row = row0 + m * 16 + kg * 4 + r;
        int col = col0 + n * 16;
        C[(size_t)row * ldc + col] = f2h(acc[m][n][r]);
      }
}

// ---------------- big GEMM: 256x256 tile, BK=64, 8 waves, wave 128x64 ------
// fp16 in. EPI 0 = fp32 out; 1 = fp16 out. (R11 schedule: best measured.)
// LDS 128KB = 2 bufs x (A 32KB + B 32KB). 8-slot XOR involution swizzle,
// zero bank conflicts (verified R11). One vmcnt(0)+barrier per K-tile.
template<int EPI>
__global__ __launch_bounds__(512, 1) void gemm256(
    const u16* __restrict__ A, int lda,
    const u16* __restrict__ B, int ldb,
    void* __restrict__ C0z, int l0, void* __restrict__ C1z, int l1,
    void* __restrict__ C2z, int l2, void* __restrict__ C3z, int l3,
    int K){
  __shared__ __align__(16) u16 sm[2 * 32768];

  const int tid = threadIdx.x;
  const int lane = tid & 63, wave = tid >> 6;
  const int wr = wave >> 2, wc = wave & 3;        // 2 x 4 waves
  const int lr = lane & 15, kg = lane >> 4;
  const int g7 = lr & 7;

  const int nwg = gridDim.x * gridDim.y;
  const int id = blockIdx.y * gridDim.x + blockIdx.x;
  const int chunk = nwg >> 3;
  const int swz = (id & 7) * chunk + (id >> 3);
  const int bx = swz % gridDim.x, by = swz / gridDim.x;
  const int m0 = by * 256, n0 = bx * 256;

  A += (size_t)blockIdx.z * (size_t)K;
  B += (size_t)blockIdx.z * (size_t)K;
  void* Cp; int ldc;
  if (blockIdx.z == 0){ Cp = C0z; ldc = l0; }
  else if (blockIdx.z == 1){ Cp = C1z; ldc = l1; }
  else if (blockIdx.z == 2){ Cp = C2z; ldc = l2; }
  else { Cp = C3z; ldc = l3; }

  auto STAGE = [&](int buf, int k0){
    #pragma unroll
    for (int rd = 0; rd < 8; ++rd){
      int p = rd >> 2;
      int r0 = (rd & 3) * 64 + wave * 8;
      const u16* g = p ? B : A;
      int ld = p ? ldb : lda;
      int rb = p ? n0 : m0;
      int grow = rb + r0 + (lane >> 3);
      int gch = (lane & 7) ^ (lane >> 3);
      const u16* src = g + (size_t)grow * ld + k0 + gch * 8;
      u16* dst = &sm[(size_t)buf * 32768 + p * 16384 + r0 * 64];
      gload16(src, dst);
    }
  };

  f32x4 acc[8][4];
  #pragma unroll
  for (int m = 0; m < 8; m++)
    #pragma unroll
    for (int n = 0; n < 4; n++)
      acc[m][n] = (f32x4){0.f, 0.f, 0.f, 0.f};

  const int KT = K >> 6;
  STAGE(0, 0);

  int bufc = 0;
  for (int kt = 0; kt < KT; ++kt){
    WAITV(0);
    __builtin_amdgcn_s_barrier();
    FENCE();
    if (kt + 1 < KT) STAGE(bufc ^ 1, (kt + 1) * 64);

    const u16* pA = &sm[(size_t)bufc * 32768];
    const u16* pB = pA + 16384;
    #pragma unroll
    for (int ks = 0; ks < 2; ++ks){
      f16x8 b[4], a[8];
      #pragma unroll
      for (int n = 0; n < 4; n++){
        int R = wc * 64 + n * 16 + lr;
        b[n] = *(const f16x8*)&pB[R * 64 + (((ks * 4 + kg) ^ g7) * 8)];
      }
      #pragma unroll
      for (int m = 0; m < 8; m++){
        int R = wr * 128 + m * 16 + lr;
        a[m] = *(const f16x8*)&pA[R * 64 + (((ks * 4 + kg) ^ g7) * 8)];
      }
      __builtin_amdgcn_s_setprio(1);
      #pragma unroll
      for (int m = 0; m < 8; m++)
        #pragma unroll
        for (int n = 0; n < 4; n++)
          acc[m][n] = __builtin_amdgcn_mfma_f32_16x16x32_f16(a[m], b[n], acc[m][n], 0, 0, 0);
      __builtin_amdgcn_s_setprio(0);
    }
    FENCE();
    bufc ^= 1;
  }

  const int row0 = m0 + wr * 128, col0 = n0 + wc * 64 + lr;
  #pragma unroll
  for (int m = 0; m < 8; m++)
    #pragma unroll
    for (int n = 0; n < 4; n++)
      #pragma unroll
      for (int r = 0; r < 4; r++){
        int row = row0 + m * 16 + kg * 4 + r;
        int col = col0 + n * 16;
        if (EPI == 0) ((float*)Cp)[(size_t)row * ldc + col] = acc[m][n][r];
        else          ((u16*)Cp)[(size_t)row * ldc + col] = f2h(acc[m][n][r]);
      }
}

// ---------------- reduce: dst16 = fp16(s0+s1+s2+s3) ----------------
__global__ __launch_bounds__(256) void reduce_t(u16* __restrict__ dst,
                                                const float* __restrict__ s0,
                                                const float* __restrict__ s1,
                                                const float* __restrict__ s2,
                                                const float* __restrict__ s3){
  int idx = blockIdx.x * 256 + threadIdx.x;
  float4 a = ((const float4*)s0)[idx];
  float4 b = ((const float4*)s1)[idx];
  float4 c = ((const float4*)s2)[idx];
  float4 d = ((const float4*)s3)[idx];
  ushort4 o;
  o.x = f2h((a.x + b.x) + (c.x + d.x));
  o.y = f2h((a.y + b.y) + (c.y + d.y));
  o.z = f2h((a.z + b.z) + (c.z + d.z));
  o.w = f2h((a.w + b.w) + (c.w + d.w));
  ((ushort4*)dst)[idx] = o;
}

// ---------------- reduce: out += s1 + s2 + s3 (flat fp32 slabs) ------------
__global__ __launch_bounds__(256) void reduce_pv4(float* __restrict__ out,
                                                  const float* __restrict__ s1,
                                                  const float* __restrict__ s2,
                                                  const float* __restrict__ s3){
  int idx = blockIdx.x * 256 + threadIdx.x;
  float4 a = ((const float4*)out)[idx];
  float4 b = ((const float4*)s1)[idx];
  float4 c = ((const float4*)s2)[idx];
  float4 d = ((const float4*)s3)[idx];
  float4 o;
  o.x = (a.x + b.x) + (c.x + d.x);
  o.y = (a.y + b.y) + (c.y + d.y);
  o.z = (a.z + b.z) + (c.z + d.z);
  o.w = (a.w + b.w) + (c.w + d.w);
  ((float4*)out)[idx] = o;
}

// ---------------- softmax over fp16 S rows (4096), write P fp16 in place ---
__global__ __launch_bounds__(256) void softmax16(u16* __restrict__ S){
  int row = blockIdx.x;
  _Float16* srow = (_Float16*)(S + (size_t)row * 4096);
  __shared__ float e[4096];
  __shared__ float red[4];
  int tid = threadIdx.x;

  float m = -1e30f;
  for (int i = tid * 8; i < 4096; i += 2048){
    f16x8 v = *(const f16x8*)(srow + i);
    #pragma unroll
    for (int j = 0; j < 8; j++) m = fmaxf(m, (float)v[j]);
  }
  for (int o = 32; o > 0; o >>= 1) m = fmaxf(m, __shfl_xor(m, o));
  if ((tid & 63) == 0) red[tid >> 6] = m;
  __syncthreads();
  m = fmaxf(fmaxf(red[0], red[1]), fmaxf(red[2], red[3]));

  float s = 0.f;
  for (int i = tid * 8; i < 4096; i += 2048){
    f16x8 v = *(const f16x8*)(srow + i);
    #pragma unroll
    for (int j = 0; j < 8; j++){
      float ev = __expf((float)v[j] - m);
      s += ev;
      e[i + j] = ev;
    }
  }
  for (int o = 32; o > 0; o >>= 1) s += __shfl_xor(s, o);
  __syncthreads();
  if ((tid & 63) == 0) red[tid >> 6] = s;
  __syncthreads();
  s = (red[0] + red[1]) + (red[2] + red[3]);

  float scale = 0.03125f / s;    // fold post-softmax 1/sqrt(dk)=1/32 into P
  for (int i = tid * 8; i < 4096; i += 2048){
    f16x8 o;
    #pragma unroll
    for (int j = 0; j < 8; j++) o[j] = (_Float16)(e[i + j] * scale);
    *(f16x8*)(srow + i) = o;
  }
}

extern "C" void kernel_launch(void* const* d_in, const int* in_sizes, int n_in,
                              void* d_out, int out_size, void* d_ws, size_t ws_size,
                              hipStream_t stream){
  const float* z  = (const float*)d_in[0];
  const float* Wq = (const float*)d_in[1];
  const float* Wk = (const float*)d_in[2];
  const float* Wv = (const float*)d_in[3];
  char* ws = (char*)d_ws;
  const size_t MB = 1ull << 20;

  // layout: 0-8 t16 | 8-16 z16 | 16-24 vt16 | 24-56 S/P fp16 | 56-88 PV slabs
  //         88-90 m16. prep scratch 24-56 (dead before S written).
  u16* t16   = (u16*)(ws + 0 * MB);
  u16* z16   = (u16*)(ws + 8 * MB);
  u16* vt16  = (u16*)(ws + 16 * MB);
  u16* S16   = (u16*)(ws + 24 * MB);              // fp16 [4096][4096]
  u16* m16   = (u16*)(ws + 88 * MB);
  float* pv1 = (float*)(ws + 56 * MB);            // PV partial slabs
  float* pv2 = (float*)(ws + 72 * MB);
  float* pv3 = (float*)(ws + 0 * MB);             // t16/z16 dead after S
  // prep scratch (24-56, dead before S):
  u16* wqh   = (u16*)(ws + 24 * MB);
  u16* wql   = (u16*)(ws + 26 * MB);
  u16* wkh   = (u16*)(ws + 28 * MB);
  u16* wkl   = (u16*)(ws + 30 * MB);
  u16* wvt16 = (u16*)(ws + 32 * MB);
  float* msl = (float*)(ws + 40 * MB);            // m' slabs 4x4MB (40-56)

  conv_h16<<<4096, 256, 0, stream>>>(z, z16, 4096 * 1024 / 4);
  split_wqk<<<2048, 256, 0, stream>>>(Wq, Wk, wqh, wql, wkh, wkl);
  transpose_wv16<<<dim3(16, 16), 256, 0, stream>>>(Wv, wvt16);

  // m'[m,n] = sum_a Wk[m,a] Wq[n,a]  (split, split-K=4 -> fp32 slabs)
  gemm_bt<0, 0><<<dim3(8, 8, 4), 256, 0, stream>>>(wkh, wkl, 1024,
      wqh, wql, 1024, msl, 1024, 256, (size_t)1024 * 1024);
  reduce_t<<<1024, 256, 0, stream>>>(m16, msl, msl + 1048576,
      msl + 2097152, msl + 3145728);

  // t = z16 @ m16^T  ||  v^T = Wv^T @ z^T   (one 512-block launch)
  gemm_dual<<<512, 256, 0, stream>>>(
      z16, 1024, m16, 1024, t16, 1024, 8,
      wvt16, 1024, z16, 1024, vt16, 4096, 32, 1024);

  // S = t16 @ z16^T  fp16 out  M=N=4096 K=1024
  gemm256<1><<<dim3(16, 16, 1), 512, 0, stream>>>(t16, 1024, z16, 1024,
      S16, 4096, S16, 4096, S16, 4096, S16, 4096, 1024);

  // softmax rows (fp16 in/out, in place), 1/32 folded in
  softmax16<<<4096, 256, 0, stream>>>(S16);

  // out = P @ v, split-K=4: z0 -> d_out, z1-3 -> flat fp32 slabs
  gemm256<0><<<dim3(4, 16, 4), 512, 0, stream>>>(S16, 4096, vt16, 4096,
      (float*)d_out, 1024, pv1, 1024, pv2, 1024, pv3, 1024, 1024);

  // out += pv1 + pv2 + pv3
  reduce_pv4<<<4096, 256, 0, stream>>>((float*)d_out, pv1, pv2, pv3);
}